// Round 5
// baseline (527.550 us; speedup 1.0000x reference)
//
#include <hip/hip_runtime.h>

#define MFULL 16384
#define MOUT  2048
#define H     4096
#define WS    8
#define BK    32
#define BM    256
#define BN    256
#define KSPLIT 2
#define KHALF  (H / KSPLIT)
#define NSTEP  (KHALF / BK)

typedef _Float16 f16x8 __attribute__((ext_vector_type(8)));
typedef _Float16 f16x4 __attribute__((ext_vector_type(4)));
typedef _Float16 f16x2 __attribute__((ext_vector_type(2)));
typedef float    f32x4 __attribute__((ext_vector_type(4)));
typedef float    f32x2 __attribute__((ext_vector_type(2)));

// fp8(e4m3 OCP, RNE) round-trip via HW cvt instructions
__device__ __forceinline__ void fp8_rt4(float4& v) {
    int p0 = __builtin_amdgcn_cvt_pk_fp8_f32(v.x, v.y, 0, false);
    int p1 = __builtin_amdgcn_cvt_pk_fp8_f32(v.z, v.w, 0, false);
    f32x2 r0 = __builtin_amdgcn_cvt_pk_f32_fp8(p0, false);
    f32x2 r1 = __builtin_amdgcn_cvt_pk_f32_fp8(p1, false);
    v.x = r0.x; v.y = r0.y; v.z = r1.x; v.w = r1.y;
}

__device__ __forceinline__ void async_copy16(const void* g, void* l) {
    __builtin_amdgcn_global_load_lds(
        (const __attribute__((address_space(1))) void*)g,
        (__attribute__((address_space(3))) void*)l, 16, 0, 0);
}

// Pass 1a: A'[r,k] = sum_{s=0..7} fp8(input[s*2048+r, k]), stored fp16.
__global__ void reduce_quant_a(const float* __restrict__ in,
                               _Float16* __restrict__ aq) {
    int idx = blockIdx.x * 256 + threadIdx.x;
    int r = idx >> 10;
    int k = (idx & 1023) * 4;
    const float* p = in + (size_t)r * H + k;
    float4 acc = {0.f, 0.f, 0.f, 0.f};
#pragma unroll
    for (int s = 0; s < WS; ++s) {
        float4 v = *(const float4*)(p + (size_t)s * MOUT * H);
        fp8_rt4(v);
        acc.x += v.x; acc.y += v.y; acc.z += v.z; acc.w += v.w;
    }
    f16x4 h = { (_Float16)acc.x, (_Float16)acc.y, (_Float16)acc.z, (_Float16)acc.w };
    *(f16x4*)(aq + (size_t)r * H + k) = h;
}

// Pass 1b: B^T[n,k] = fp16(fp8(weight[k,n])). 64x64 tile transpose via LDS.
__global__ void quant_transpose_b(const float* __restrict__ w,
                                  _Float16* __restrict__ bt) {
    __shared__ _Float16 tile[64][66];
    int t  = threadIdx.x;
    int n0 = blockIdx.x * 64;
    int k0 = blockIdx.y * 64;
#pragma unroll
    for (int i = 0; i < 4; ++i) {
        int lin = i * 256 + t;
        int kl = lin >> 4;
        int nl = (lin & 15) * 4;
        float4 v = *(const float4*)(w + (size_t)(k0 + kl) * H + n0 + nl);
        fp8_rt4(v);
        tile[kl][nl + 0] = (_Float16)v.x;
        tile[kl][nl + 1] = (_Float16)v.y;
        tile[kl][nl + 2] = (_Float16)v.z;
        tile[kl][nl + 3] = (_Float16)v.w;
    }
    __syncthreads();
#pragma unroll
    for (int i = 0; i < 8; ++i) {
        int lin = i * 256 + t;
        int kl = (lin & 31) * 2;
        int nl = lin >> 5;
        f16x2 hv = { tile[kl][nl], tile[kl + 1][nl] };
        *(f16x2*)(bt + (size_t)(n0 + nl) * H + k0 + kl) = hv;
    }
}

// Pass 2: partial[z][256-tile] = A'[.,zK..] @ B'[zK..,.]  (f32 partials).
//
// 256x256 block tile, SPLIT-K=2 (grid 16x8x2 = 256 blocks = 1/CU), 512
// threads = 8 waves of 128x64 wave tiles (2m x 4n). Rationale: 64x64 wave
// tiles (R2) cost 128 KB frag-reads per CU per K64 vs 1242 cyc MFMA ->
// LDS-bound 1.7x. 128x64 wave tiles cut frag bytes/FLOP 45% -> LDS ~= MFMA.
//
// BK=32, ring-4 LDS buffers (128 KB), prefetch depth 3, counted vmcnt(8)
// (NEVER 0 in main loop) -- the proven R2 recycle pattern generalized
// (ring-3/depth-2/vmcnt(6) -> ring-4/depth-3/vmcnt(8)). R2 barrier
// discipline kept: per phase [reads|stage -> BAR -> MFMA -> BAR].
//   step t: p0: stage(t+3) into buf[(t+3)&3]; read af[0..3], bf[0..3];
//               BAR; 16 MFMA (i-half 0); BAR.
//           p1: read af[4..7]; vmcnt(8) (t+1 confirmed, t+2/t+3 in
//               flight); BAR; 16 MFMA (i-half 1); BAR.
//   Recycle safety: buf[(t+3)&3] == buf[(t-1)&3]; all waves' reads of
//   step t-1 completed (consumed by its p1 MFMA) before its final BAR,
//   and stage is issued after that BAR.
// Swizzle (64 B rows, 4 slots of 16 B): slot s holds k-chunk
// g = s ^ ((row>>2)&3); staging pre-swizzles the GLOBAL source, LDS dest
// linear (gload_lds requirement); frag read uses the same XOR.
__global__ __launch_bounds__(512, 2) void gemm_rs(
    const _Float16* __restrict__ A, const _Float16* __restrict__ Bt,
    float* __restrict__ part) {
    __shared__ __align__(16) _Float16 As[4][BM * BK];   // 4 x 16 KB
    __shared__ __align__(16) _Float16 Bs[4][BN * BK];   // 4 x 16 KB

    const int tid  = threadIdx.x;
    const int wid  = tid >> 6;           // 0..7
    const int lane = tid & 63;
    const int quad = lane >> 4;
    const int l16  = lane & 15;
    const int bm   = blockIdx.y * BM;
    const int bn   = blockIdx.x * BN;
    const int wm   = (wid >> 2) * 128;   // 0,128
    const int wn   = (wid & 3) * 64;     // 0,64,128,192
    const size_t kbase = (size_t)blockIdx.z * KHALF;

    f32x4 acc[8][4] = {};

    const _Float16* Ab = A  + (size_t)bm * H;
    const _Float16* Bb = Bt + (size_t)bn * H;

    // staging: each tile (256 rows x 32 k f16 = 16 KB) = 1024 16B chunks,
    // 2/thread. chunk c: row = c>>2, slot = c&3, g = slot ^ ((row>>2)&3);
    // LDS dest = c*16 (lane-linear per wave). A and B use the same formula.
    size_t ga[2]; int la[2];
#pragma unroll
    for (int u = 0; u < 2; ++u) {
        int c = u * 512 + tid;
        int row = c >> 2, slot = c & 3;
        int g = slot ^ ((row >> 2) & 3);
        ga[u] = (size_t)row * H + g * 8;   // elements (fp16)
        la[u] = c * 16;                    // bytes
    }

    // fragment offsets (elements): k-chunk q = quad lives at
    // slot s = q ^ ((row>>2)&3)
    int aOff[8], bOff[4];
#pragma unroll
    for (int i = 0; i < 8; ++i) {
        int rowA = wm + i * 16 + l16;
        int sA = quad ^ ((rowA >> 2) & 3);
        aOff[i] = rowA * BK + sA * 8;
    }
#pragma unroll
    for (int j = 0; j < 4; ++j) {
        int rowB = wn + j * 16 + l16;
        int sB = quad ^ ((rowB >> 2) & 3);
        bOff[j] = rowB * BK + sB * 8;
    }

#define FENCE asm volatile("" ::: "memory")
#define BAR   __builtin_amdgcn_s_barrier()
#define WAIT8 asm volatile("s_waitcnt vmcnt(8)" ::: "memory")
#define WAIT4 asm volatile("s_waitcnt vmcnt(4)" ::: "memory")
#define WAIT0 asm volatile("s_waitcnt vmcnt(0)" ::: "memory")
#define WAITN ((void)0)

#define STEP(T, DO_STAGE, WAITSTMT)                                         \
    {                                                                       \
        const int cb_ = (T) & 3;                                            \
        const _Float16* aP_ = &As[cb_][0];                                  \
        const _Float16* bP_ = &Bs[cb_][0];                                  \
        /* p0: stage t+3; read af[0..3], bf[0..3] */                        \
        if (DO_STAGE) {                                                     \
            char* aL_ = (char*)&As[((T) + 3) & 3][0];                       \
            char* bL_ = (char*)&Bs[((T) + 3) & 3][0];                       \
            const size_t ko_ = kbase + (size_t)((T) + 3) * BK;              \
            _Pragma("unroll")                                               \
            for (int u = 0; u < 2; ++u)                                     \
                async_copy16(Ab + ga[u] + ko_, aL_ + la[u]);                \
            _Pragma("unroll")                                               \
            for (int u = 0; u < 2; ++u)                                     \
                async_copy16(Bb + ga[u] + ko_, bL_ + la[u]);                \
        }                                                                   \
        f16x8 bf[4], af[4];                                                 \
        _Pragma("unroll")                                                   \
        for (int j = 0; j < 4; ++j) bf[j] = *(const f16x8*)(bP_ + bOff[j]); \
        _Pragma("unroll")                                                   \
        for (int ii = 0; ii < 4; ++ii)                                      \
            af[ii] = *(const f16x8*)(aP_ + aOff[ii]);                       \
        FENCE; BAR;                                                         \
        __builtin_amdgcn_s_setprio(1);                                      \
        _Pragma("unroll")                                                   \
        for (int j = 0; j < 4; ++j)                                         \
            _Pragma("unroll")                                               \
            for (int ii = 0; ii < 4; ++ii)                                  \
                acc[ii][j] = __builtin_amdgcn_mfma_f32_16x16x32_f16(        \
                    af[ii], bf[j], acc[ii][j], 0, 0, 0);                    \
        __builtin_amdgcn_s_setprio(0);                                      \
        FENCE; BAR;                                                         \
        /* p1: read af[4..7]; counted wait; MFMA i-half 1 */                \
        _Pragma("unroll")                                                   \
        for (int ii = 0; ii < 4; ++ii)                                      \
            af[ii] = *(const f16x8*)(aP_ + aOff[4 + ii]);                   \
        WAITSTMT;                                                           \
        FENCE; BAR;                                                         \
        __builtin_amdgcn_s_setprio(1);                                      \
        _Pragma("unroll")                                                   \
        for (int j = 0; j < 4; ++j)                                         \
            _Pragma("unroll")                                               \
            for (int ii = 0; ii < 4; ++ii)                                  \
                acc[4 + ii][j] = __builtin_amdgcn_mfma_f32_16x16x32_f16(    \
                    af[ii], bf[j], acc[4 + ii][j], 0, 0, 0);                \
        __builtin_amdgcn_s_setprio(0);                                      \
        FENCE; BAR;                                                         \
    }

    // prologue: stage K-tiles 0,1,2 into bufs 0,1,2 (12 loads); confirm
    // buf0 (vmcnt(8): oldest 4 done, 8 in flight).
#pragma unroll
    for (int tt = 0; tt < 3; ++tt) {
        char* aL = (char*)&As[tt][0];
        char* bL = (char*)&Bs[tt][0];
        const size_t ko = kbase + (size_t)tt * BK;
#pragma unroll
        for (int u = 0; u < 2; ++u) async_copy16(Ab + ga[u] + ko, aL + la[u]);
#pragma unroll
        for (int u = 0; u < 2; ++u) async_copy16(Bb + ga[u] + ko, bL + la[u]);
    }
    WAIT8;
    BAR;
    FENCE;

    for (int t = 0; t < NSTEP - 3; ++t) {
        STEP(t, 1, WAIT8);
    }
    STEP(NSTEP - 3, 0, WAIT4);
    STEP(NSTEP - 2, 0, WAIT0);
    STEP(NSTEP - 1, 0, WAITN);

#undef FENCE
#undef BAR
#undef WAIT8
#undef WAIT4
#undef WAIT0
#undef WAITN
#undef STEP

    // Epilogue: raw f32 partials (scale+round deferred to finalize).
    // D[row=(lane>>4)*4+r][col=lane&15] per 16x16 tile.
    float* P = part + (size_t)blockIdx.z * MOUT * H;
#pragma unroll
    for (int j = 0; j < 4; ++j) {
        int col = bn + wn + j * 16 + l16;
#pragma unroll
        for (int i = 0; i < 8; ++i) {
#pragma unroll
            for (int r = 0; r < 4; ++r) {
                int row = bm + wm + i * 16 + quad * 4 + r;
                P[(size_t)row * H + col] = acc[i][j][r];
            }
        }
    }
}

// Pass 3: out = fp16_round((P0 + P1) * scale_b), stored as float.
__global__ void finalize_rs(const float* __restrict__ p0,
                            const float* __restrict__ p1,
                            const float* __restrict__ scale_b,
                            float* __restrict__ out) {
    size_t idx = (size_t)blockIdx.x * 256 + threadIdx.x;
    size_t e = idx * 4;
    int col = (int)(e & (H - 1));
    float4 a = *(const float4*)(p0 + e);
    float4 b = *(const float4*)(p1 + e);
    float4 s = *(const float4*)(scale_b + col);
    float4 r;
    r.x = (float)(_Float16)((a.x + b.x) * s.x);
    r.y = (float)(_Float16)((a.y + b.y) * s.y);
    r.z = (float)(_Float16)((a.z + b.z) * s.z);
    r.w = (float)(_Float16)((a.w + b.w) * s.w);
    *(float4*)(out + e) = r;
}

extern "C" void kernel_launch(void* const* d_in, const int* in_sizes, int n_in,
                              void* d_out, int out_size, void* d_ws, size_t ws_size,
                              hipStream_t stream) {
    const float* input   = (const float*)d_in[0];   // [16384, 4096] fp32
    const float* weight  = (const float*)d_in[1];   // [4096, 4096] fp32
    const float* scale_b = (const float*)d_in[2];   // [1, 4096] fp32
    float* out = (float*)d_out;                     // [2048, 4096] (fp16 values)

    _Float16* aq = (_Float16*)d_ws;                             // 16 MB
    _Float16* bt = aq + (size_t)MOUT * H;                       // 32 MB
    float* part  = (float*)((char*)d_ws + (size_t)48 * 1024 * 1024); // 64 MB

    reduce_quant_a<<<(MOUT * H / 4) / 256, 256, 0, stream>>>(input, aq);
    quant_transpose_b<<<dim3(H / 64, H / 64), 256, 0, stream>>>(weight, bt);
    gemm_rs<<<dim3(H / BN, MOUT / BM, KSPLIT), 512, 0, stream>>>(aq, bt, part);
    finalize_rs<<<(MOUT * H / 4) / 256, 256, 0, stream>>>(
        part, part + (size_t)MOUT * H, scale_b, out);
}

// Round 6
// 496.644 us; speedup vs baseline: 1.0622x; 1.0622x over previous
//
#include <hip/hip_runtime.h>

#define MFULL 16384
#define MOUT  2048
#define H     4096
#define WS    8
#define BK    64
#define BM    128
#define BN    256
#define NT    (H / BK)

typedef _Float16 f16x8 __attribute__((ext_vector_type(8)));
typedef _Float16 f16x4 __attribute__((ext_vector_type(4)));
typedef _Float16 f16x2 __attribute__((ext_vector_type(2)));
typedef float    f32x4 __attribute__((ext_vector_type(4)));
typedef float    f32x2 __attribute__((ext_vector_type(2)));

// fp8(e4m3 OCP, RNE) round-trip via HW cvt instructions
__device__ __forceinline__ void fp8_rt4(float4& v) {
    int p0 = __builtin_amdgcn_cvt_pk_fp8_f32(v.x, v.y, 0, false);
    int p1 = __builtin_amdgcn_cvt_pk_fp8_f32(v.z, v.w, 0, false);
    f32x2 r0 = __builtin_amdgcn_cvt_pk_f32_fp8(p0, false);
    f32x2 r1 = __builtin_amdgcn_cvt_pk_f32_fp8(p1, false);
    v.x = r0.x; v.y = r0.y; v.z = r1.x; v.w = r1.y;
}

__device__ __forceinline__ void async_copy16(const void* g, void* l) {
    __builtin_amdgcn_global_load_lds(
        (const __attribute__((address_space(1))) void*)g,
        (__attribute__((address_space(3))) void*)l, 16, 0, 0);
}

// Pass 1 (FUSED): blocks [0,8192) do the A-reduce-quant; blocks
// [8192,12288) do the B quant-transpose. Independent work, one launch:
// saves a launch gap and overlaps B's 96 MB with A's 272 MB tail.
__global__ void fused_pass1(const float* __restrict__ in,
                            const float* __restrict__ w,
                            _Float16* __restrict__ aq,
                            _Float16* __restrict__ bt) {
    __shared__ _Float16 tile[64][66];
    int bid = blockIdx.x;
    int t   = threadIdx.x;
    if (bid < 8192) {
        // A'[r,k] = sum_{s=0..7} fp8(input[s*2048+r, k]), stored fp16.
        int idx = bid * 256 + t;
        int r = idx >> 10;
        int k = (idx & 1023) * 4;
        const float* p = in + (size_t)r * H + k;
        float4 acc = {0.f, 0.f, 0.f, 0.f};
#pragma unroll
        for (int s = 0; s < WS; ++s) {
            float4 v = *(const float4*)(p + (size_t)s * MOUT * H);
            fp8_rt4(v);
            acc.x += v.x; acc.y += v.y; acc.z += v.z; acc.w += v.w;
        }
        f16x4 h = { (_Float16)acc.x, (_Float16)acc.y,
                    (_Float16)acc.z, (_Float16)acc.w };
        *(f16x4*)(aq + (size_t)r * H + k) = h;
    } else {
        // B^T[n,k] = fp16(fp8(weight[k,n])). 64x64 tile transpose via LDS.
        int id = bid - 8192;
        int n0 = (id & 63) * 64;
        int k0 = (id >> 6) * 64;
#pragma unroll
        for (int i = 0; i < 4; ++i) {
            int lin = i * 256 + t;
            int kl = lin >> 4;
            int nl = (lin & 15) * 4;
            float4 v = *(const float4*)(w + (size_t)(k0 + kl) * H + n0 + nl);
            fp8_rt4(v);
            tile[kl][nl + 0] = (_Float16)v.x;
            tile[kl][nl + 1] = (_Float16)v.y;
            tile[kl][nl + 2] = (_Float16)v.z;
            tile[kl][nl + 3] = (_Float16)v.w;
        }
        __syncthreads();
#pragma unroll
        for (int i = 0; i < 8; ++i) {
            int lin = i * 256 + t;
            int kl = (lin & 31) * 2;
            int nl = lin >> 5;
            f16x2 hv = { tile[kl][nl], tile[kl + 1][nl] };
            *(f16x2*)(bt + (size_t)(n0 + nl) * H + k0 + kl) = hv;
        }
    }
}

// Pass 2: C[2048,4096] = A' @ B' (B' as B^T [N][K]), scale_b fused epilogue.
// R2-champion structure, byte-for-byte. 4-phase K-step (T3+T4+T5),
// 128x256 tile, 512 threads (8 waves, 2x4 of 64x64), grid 16x16 = 256
// blocks = 1 block/CU.
//   - 3 LDS buffers (144 KB), prefetch depth 2; per K-step the 6 staging
//     loads (2 A + 4 B per thread) are spread over phases 0..2; phase 3
//     waits s_waitcnt vmcnt(6) -- NEVER 0 in the main loop.
//   - each phase: {ds_read fragment subtile; 2x global_load_lds; barrier;
//     setprio(1); 8 MFMA; setprio(0); barrier}. The phase split creates
//     wave role diversity per SIMD -- the m196/m218 mechanism. (R4's
//     reduced-barrier and read-ahead variants both regressed: the full
//     lockstep is load-bearing.)
// XOR swizzle: LDS slot s of row holds global k-chunk kc = s ^ ((row>>1)&7)
// -> fragment ds_read_b128 lands 2 lanes/bank (free).
__global__ __launch_bounds__(512, 2) void gemm_rs(
    const _Float16* __restrict__ A, const _Float16* __restrict__ Bt,
    const float* __restrict__ scale_b, float* __restrict__ out) {
    __shared__ _Float16 As[3][BM * BK];   // 3 x 16 KB
    __shared__ _Float16 Bs[3][BN * BK];   // 3 x 32 KB

    const int tid  = threadIdx.x;
    const int wid  = tid >> 6;           // 0..7
    const int lane = tid & 63;
    const int quad = lane >> 4;
    const int l16  = lane & 15;
    const int bm   = blockIdx.y * BM;
    const int bn   = blockIdx.x * BN;
    const int wm   = (wid >> 2) * 64;    // 0,64
    const int wn   = (wid & 3) * 64;     // 0,64,128,192

    f32x4 acc[4][4] = {};

    const _Float16* Ab = A  + (size_t)bm * H;
    const _Float16* Bb = Bt + (size_t)bn * H;

    size_t gaA[2]; int laA[2];
    size_t gaB[4]; int laB[4];
#pragma unroll
    for (int u = 0; u < 2; ++u) {
        int c = u * 512 + tid;
        int row = c >> 3, slot = c & 7;
        int kc = slot ^ ((row >> 1) & 7);
        gaA[u] = (size_t)row * H + kc * 8;
        laA[u] = c * 16;
    }
#pragma unroll
    for (int u = 0; u < 4; ++u) {
        int c = u * 512 + tid;
        int row = c >> 3, slot = c & 7;
        int kc = slot ^ ((row >> 1) & 7);
        gaB[u] = (size_t)row * H + kc * 8;
        laB[u] = c * 16;
    }

    int aOff[4][2], bOff[4][2];
#pragma unroll
    for (int i = 0; i < 4; ++i) {
        int rowA = wm + i * 16 + l16;
        int rowB = wn + i * 16 + l16;
#pragma unroll
        for (int h = 0; h < 2; ++h) {
            int sA = (h * 4 + quad) ^ ((rowA >> 1) & 7);
            int sB = (h * 4 + quad) ^ ((rowB >> 1) & 7);
            aOff[i][h] = rowA * BK + sA * 8;
            bOff[i][h] = rowB * BK + sB * 8;
        }
    }

#define FENCE asm volatile("" ::: "memory")
#define BAR   __builtin_amdgcn_s_barrier()

#define MG(afv, bfv, j)                                                     \
    _Pragma("unroll")                                                       \
    for (int i = 0; i < 4; ++i)                                             \
        acc[i][j] = __builtin_amdgcn_mfma_f32_16x16x32_f16(                 \
            afv[i], bfv, acc[i][j], 0, 0, 0);

#define STAGE_ALL(bufi, koff)                                               \
    {                                                                       \
        char* aL_ = (char*)&As[bufi][0];                                    \
        char* bL_ = (char*)&Bs[bufi][0];                                    \
        _Pragma("unroll")                                                   \
        for (int u = 0; u < 2; ++u)                                         \
            async_copy16(Ab + gaA[u] + (koff), aL_ + laA[u]);               \
        _Pragma("unroll")                                                   \
        for (int u = 0; u < 4; ++u)                                         \
            async_copy16(Bb + gaB[u] + (koff), bL_ + laB[u]);               \
    }

#define COMPUTE_MONO(bufi)                                                  \
    {                                                                       \
        const _Float16* aP_ = &As[bufi][0];                                 \
        const _Float16* bP_ = &Bs[bufi][0];                                 \
        f16x8 af[4][2], bf[4][2];                                           \
        _Pragma("unroll")                                                   \
        for (int i = 0; i < 4; ++i) {                                       \
            _Pragma("unroll")                                               \
            for (int h = 0; h < 2; ++h) {                                   \
                af[i][h] = *(const f16x8*)(aP_ + aOff[i][h]);               \
                bf[i][h] = *(const f16x8*)(bP_ + bOff[i][h]);               \
            }                                                               \
        }                                                                   \
        __builtin_amdgcn_s_setprio(1);                                      \
        _Pragma("unroll")                                                   \
        for (int h = 0; h < 2; ++h)                                         \
            _Pragma("unroll")                                               \
            for (int i = 0; i < 4; ++i)                                     \
                _Pragma("unroll")                                           \
                for (int j = 0; j < 4; ++j)                                 \
                    acc[i][j] = __builtin_amdgcn_mfma_f32_16x16x32_f16(     \
                        af[i][h], bf[j][h], acc[i][j], 0, 0, 0);            \
        __builtin_amdgcn_s_setprio(0);                                      \
    }

    // prologue: 2 K-tiles in flight; wait for buf0 only (12 -> 6 outstanding)
    STAGE_ALL(0, 0);
    STAGE_ALL(1, BK);
    asm volatile("s_waitcnt vmcnt(6)" ::: "memory");
    BAR;
    FENCE;

    // invariant at loop top: outstanding = 6 loads of K-tile t+1
    int cur = 0;
    for (int t = 0; t < NT - 2; ++t) {
        int b2 = cur + 2; if (b2 >= 3) b2 -= 3;
        const _Float16* aP = &As[cur][0];
        const _Float16* bP = &Bs[cur][0];
        char* aL = (char*)&As[b2][0];
        char* bL = (char*)&Bs[b2][0];
        const size_t ko2 = (size_t)(t + 2) * BK;

        f16x8 af0[4], af1[4];

        // ---- phase 0: A frags h=0, B cols 0-1 h=0; stage A ----
#pragma unroll
        for (int i = 0; i < 4; ++i) af0[i] = *(const f16x8*)(aP + aOff[i][0]);
        f16x8 b00 = *(const f16x8*)(bP + bOff[0][0]);
        f16x8 b10 = *(const f16x8*)(bP + bOff[1][0]);
#pragma unroll
        for (int u = 0; u < 2; ++u) async_copy16(Ab + gaA[u] + ko2, aL + laA[u]);
        FENCE; BAR;
        __builtin_amdgcn_s_setprio(1);
        MG(af0, b00, 0);
        MG(af0, b10, 1);
        __builtin_amdgcn_s_setprio(0);
        FENCE; BAR;

        // ---- phase 1: B cols 2-3 h=0; stage B(0,1) ----
        f16x8 b20 = *(const f16x8*)(bP + bOff[2][0]);
        f16x8 b30 = *(const f16x8*)(bP + bOff[3][0]);
#pragma unroll
        for (int u = 0; u < 2; ++u) async_copy16(Bb + gaB[u] + ko2, bL + laB[u]);
        FENCE; BAR;
        __builtin_amdgcn_s_setprio(1);
        MG(af0, b20, 2);
        MG(af0, b30, 3);
        __builtin_amdgcn_s_setprio(0);
        FENCE; BAR;

        // ---- phase 2: A frags h=1, B cols 0-1 h=1; stage B(2,3) ----
#pragma unroll
        for (int i = 0; i < 4; ++i) af1[i] = *(const f16x8*)(aP + aOff[i][1]);
        f16x8 b01 = *(const f16x8*)(bP + bOff[0][1]);
        f16x8 b11 = *(const f16x8*)(bP + bOff[1][1]);
#pragma unroll
        for (int u = 2; u < 4; ++u) async_copy16(Bb + gaB[u] + ko2, bL + laB[u]);
        FENCE; BAR;
        __builtin_amdgcn_s_setprio(1);
        MG(af1, b01, 0);
        MG(af1, b11, 1);
        __builtin_amdgcn_s_setprio(0);
        FENCE; BAR;

        // ---- phase 3: B cols 2-3 h=1; counted vmcnt (t+1 done, t+2 fly) ----
        f16x8 b21 = *(const f16x8*)(bP + bOff[2][1]);
        f16x8 b31 = *(const f16x8*)(bP + bOff[3][1]);
        asm volatile("s_waitcnt vmcnt(6)" ::: "memory");
        FENCE; BAR;
        __builtin_amdgcn_s_setprio(1);
        MG(af1, b21, 2);
        MG(af1, b31, 3);
        __builtin_amdgcn_s_setprio(0);
        FENCE; BAR;

        cur = cur + 1; if (cur >= 3) cur = 0;
    }

    // tail: t = NT-2 (data ready; 6 loads of NT-1 outstanding), then NT-1
    COMPUTE_MONO(cur);
    asm volatile("s_waitcnt vmcnt(0)" ::: "memory");
    BAR;
    FENCE;
    cur = cur + 1; if (cur >= 3) cur = 0;
    COMPUTE_MONO(cur);

#undef FENCE
#undef BAR
#undef MG
#undef STAGE_ALL
#undef COMPUTE_MONO

    // Epilogue: D[row=(lane>>4)*4+r][col=lane&15] per 16x16 tile, fp16-round
#pragma unroll
    for (int j = 0; j < 4; ++j) {
        int col = bn + wn + j * 16 + l16;
        float sb = scale_b[col];
#pragma unroll
        for (int i = 0; i < 4; ++i) {
#pragma unroll
            for (int r = 0; r < 4; ++r) {
                int row = bm + wm + i * 16 + quad * 4 + r;
                float v = acc[i][j][r] * sb;
                out[(size_t)row * H + col] = (float)(_Float16)v;
            }
        }
    }
}

extern "C" void kernel_launch(void* const* d_in, const int* in_sizes, int n_in,
                              void* d_out, int out_size, void* d_ws, size_t ws_size,
                              hipStream_t stream) {
    const float* input   = (const float*)d_in[0];   // [16384, 4096] fp32
    const float* weight  = (const float*)d_in[1];   // [4096, 4096] fp32
    const float* scale_b = (const float*)d_in[2];   // [1, 4096] fp32
    float* out = (float*)d_out;                     // [2048, 4096] (fp16 values)

    _Float16* aq = (_Float16*)d_ws;                 // 16 MB
    _Float16* bt = aq + (size_t)MOUT * H;           // 32 MB

    fused_pass1<<<8192 + 4096, 256, 0, stream>>>(input, weight, aq, bt);
    gemm_rs<<<dim3(H / BN, MOUT / BM), 512, 0, stream>>>(aq, bt, scale_b, out);
}